// Round 18
// baseline (90.744 us; speedup 1.0000x reference)
//
#include <hip/hip_runtime.h>

// Problem constants (from reference)
constexpr int B_  = 16;
constexpr int NV_ = 10475;
constexpr int F_  = 20908;
constexpr int P_  = F_ * 8;              // 167264 pairs per batch (even)
constexpr float LINEAR_MAX_ = 1000.0f;

constexpr int REC_PB_  = 82;             // face-record blocks per batch (82*256 >= F_)
constexpr int PAIR_PB_ = 82;             // pair blocks per batch (82*256*8 >= P_)

// d_ws layout:
//   tbl  : 64 B per (b,f) record = 21.4 MB   (offset 0)
//   part : float[B_*PAIR_PB_]                 (offset 21.4 MB)
// Record (b,f): [0]{n.xyz, c·n} [1]{v0.xyz,v1.x} [2]{v1.yz,v2.xy} [3]{v2.z,-,-,-}
//
// Sync discipline (measured): kernel boundaries only. grid.sync() cost ~130 µs
// (R14) and ticket+acq/rel atomics ~100 µs (R15) on this chip — never again.

// XCD b-locality swizzle (consecutive bids round-robin the 8 XCDs): each XCD
// serves 2 batches -> per-XCD table slice 2.7 MB, L2-resident. Heuristic only;
// correctness never depends on it.
__device__ __forceinline__ void swz(int bid, int& b, int& px) {
    const int xcd = bid & 7;
    const int j   = bid >> 3;
    b  = xcd + ((j & 1) << 3);
    px = j >> 1;
}

// Pass 1: build 64B records. Stage in LDS with stride-5 padding (R14 profile:
// 503K bank conflicts at stride-4; R17 confirmed the pad is a ~2.5 µs win),
// then write coalesced (4 sequential-line float4 stores per wave).
__global__ __launch_bounds__(256) void face_rec_kernel(
    const float* __restrict__ v,        // (B, NV, 3)
    const int*   __restrict__ faces,    // (F, 3)
    float4*      __restrict__ tbl)
{
    __shared__ float4 lds4[256 * 5];    // record r, word j at [r*5+j]; 20 KB

    int b, px; swz(blockIdx.x, b, px);
    const int t  = threadIdx.x;
    const int f0 = px * 256;
    const int f  = f0 + t;
    const int fc = (f < F_) ? f : 0;    // clamp tail (no OOB read)

    const float* __restrict__ vb = v + (size_t)b * (NV_ * 3);
    const int i0 = faces[fc * 3 + 0] * 3;
    const int i1 = faces[fc * 3 + 1] * 3;
    const int i2 = faces[fc * 3 + 2] * 3;

    const float v0x = vb[i0 + 0], v0y = vb[i0 + 1], v0z = vb[i0 + 2];
    const float v1x = vb[i1 + 0], v1y = vb[i1 + 1], v1z = vb[i1 + 2];
    const float v2x = vb[i2 + 0], v2y = vb[i2 + 1], v2z = vb[i2 + 2];

    const float third = 1.0f / 3.0f;
    const float cx = (v0x + v1x + v2x) * third;
    const float cy = (v0y + v1y + v2y) * third;
    const float cz = (v0z + v1z + v2z) * third;

    const float e1x = v1x - v0x, e1y = v1y - v0y, e1z = v1z - v0z;
    const float e2x = v2x - v0x, e2y = v2y - v0y, e2z = v2z - v0z;
    float nx = e1y * e2z - e1z * e2y;
    float ny = e1z * e2x - e1x * e2z;
    float nz = e1x * e2y - e1y * e2x;
    const float inv = 1.0f / (sqrtf(nx * nx + ny * ny + nz * nz) + 1e-12f);
    nx *= inv; ny *= inv; nz *= inv;

    lds4[t * 5 + 0] = make_float4(nx, ny, nz, cx * nx + cy * ny + cz * nz);
    lds4[t * 5 + 1] = make_float4(v0x, v0y, v0z, v1x);
    lds4[t * 5 + 2] = make_float4(v1y, v1z, v2x, v2y);
    lds4[t * 5 + 3] = make_float4(v2z, 0.0f, 0.0f, 0.0f);
    __syncthreads();

    // Coalesced write-out; guard tail so batch b never writes past its region.
    const int vrec  = F_ - f0;
    const int limit = ((vrec < 256) ? vrec : 256) * 4;
    float4* dst = tbl + ((size_t)b * F_ + f0) * 4;
    #pragma unroll
    for (int j = 0; j < 4; ++j) {
        const int e = j * 256 + t;
        if (e < limit) dst[e] = lds4[(e >> 2) * 5 + (e & 3)];
    }
}

// Pass 2: 8 pairs per thread via 4 coalesced int4 loads (2 pairs each) —
// 4.5 VMEM/pair vs R17's 5, and half the blocks (1312). Per valid pair:
// 4 scattered float4 loads touching 2 cache lines. No atomics.
__global__ __launch_bounds__(256) void pen_pairs_kernel(
    const int*    __restrict__ coll,    // (B, P, 2) as ints
    const float4* __restrict__ tbl,
    float*        __restrict__ part)    // (B, PAIR_PB_)
{
    int b, px; swz(blockIdx.x, b, px);
    const int t = threadIdx.x;

    const int4*   __restrict__ c4 = (const int4*)(coll + (size_t)b * P_ * 2);
    const float4* __restrict__ bt = tbl + (size_t)b * F_ * 4;

    float psi2 = 0.0f;
    const int ibase = px * 1024;        // block covers 1024 int4 = 2048 pairs

    #pragma unroll
    for (int k = 0; k < 4; ++k) {
        const int idx = ibase + (k << 8) + t;
        if (idx < (P_ >> 1)) {
            const int4 pp = c4[idx];

            #pragma unroll
            for (int h = 0; h < 2; ++h) {
                const int ix = (h == 0) ? pp.x : pp.z;   // intruder
                const int iy = (h == 0) ? pp.y : pp.w;   // receiver
                const float m = ((ix | iy) >= 0) ? 1.0f : 0.0f;
                const int fR = (iy > 0) ? iy : 0;
                const int fI = (ix > 0) ? ix : 0;

                const float4 nd = bt[fR * 4 + 0];
                const float4 L0 = bt[fI * 4 + 1];
                const float4 L1 = bt[fI * 4 + 2];
                const float4 L2 = bt[fI * 4 + 3];

                float s = 0.0f;
                float t0 = nd.w - (L0.x * nd.x + L0.y * nd.y + L0.z * nd.z);
                t0 = fminf(fmaxf(t0, 0.0f), LINEAR_MAX_);
                s = fmaf(t0, t0, s);
                float t1 = nd.w - (L0.w * nd.x + L1.x * nd.y + L1.y * nd.z);
                t1 = fminf(fmaxf(t1, 0.0f), LINEAR_MAX_);
                s = fmaf(t1, t1, s);
                float t2 = nd.w - (L1.z * nd.x + L1.w * nd.y + L2.x * nd.z);
                t2 = fminf(fmaxf(t2, 0.0f), LINEAR_MAX_);
                s = fmaf(t2, t2, s);

                psi2 = fmaf(m, s, psi2);
            }
        }
    }

    #pragma unroll
    for (int off = 32; off > 0; off >>= 1)
        psi2 += __shfl_down(psi2, off, 64);

    __shared__ float wsum[4];
    const int lane = t & 63;
    const int wid  = t >> 6;
    if (lane == 0) wsum[wid] = psi2;
    __syncthreads();

    if (t == 0)
        part[b * PAIR_PB_ + px] = wsum[0] + wsum[1] + wsum[2] + wsum[3];
}

// Pass 3: block b sums its 82 partials, writes out[b] (overwrites poison).
__global__ __launch_bounds__(128) void final_reduce_kernel(
    const float* __restrict__ part,     // (B, PAIR_PB_)
    float*       __restrict__ out)      // (B,)
{
    const int b = blockIdx.x;
    const int t = threadIdx.x;

    float s = (t < PAIR_PB_) ? part[b * PAIR_PB_ + t] : 0.0f;

    #pragma unroll
    for (int off = 32; off > 0; off >>= 1)
        s += __shfl_down(s, off, 64);

    __shared__ float wsum[2];
    if ((t & 63) == 0) wsum[t >> 6] = s;
    __syncthreads();

    if (t == 0) out[b] = wsum[0] + wsum[1];
}

extern "C" void kernel_launch(void* const* d_in, const int* in_sizes, int n_in,
                              void* d_out, int out_size, void* d_ws, size_t ws_size,
                              hipStream_t stream) {
    const float* v     = (const float*)d_in[0];
    const int*   faces = (const int*)d_in[1];
    const int*   coll  = (const int*)d_in[2];
    float* out = (float*)d_out;

    float4* tbl  = (float4*)d_ws;
    float*  part = (float*)((char*)d_ws + (size_t)B_ * F_ * 64);

    dim3 block(256);
    face_rec_kernel   <<<dim3(16 * REC_PB_),  block, 0, stream>>>(v, faces, tbl);   // 1312
    pen_pairs_kernel  <<<dim3(16 * PAIR_PB_), block, 0, stream>>>(coll, tbl, part); // 1312
    final_reduce_kernel<<<dim3(B_), dim3(128), 0, stream>>>(part, out);
}